// Round 12
// baseline (130.750 us; speedup 1.0000x reference)
//
#include <hip/hip_runtime.h>
#include <hip/hip_bf16.h>
#include <stdint.h>

typedef __attribute__((ext_vector_type(8))) short s16x8;          // 8 bf16 (4 VGPRs)
typedef __attribute__((ext_vector_type(8))) unsigned short u16x8;
typedef __attribute__((ext_vector_type(4))) float f32x4;
typedef __attribute__((ext_vector_type(2))) float f32x2;
typedef __attribute__((ext_vector_type(4))) unsigned int u32x4;

#define D_FEAT 128
#define H2 128

__device__ __forceinline__ unsigned short f2bf(float f) {
  uint32_t u = __float_as_uint(f);
  return (unsigned short)((u + 0x7fffu + ((u >> 16) & 1u)) >> 16);  // RNE
}
__device__ __forceinline__ float bf2f(unsigned short s) {
  return __uint_as_float((uint32_t)s << 16);
}
// two packed bf16 -> f32x2 {lo, hi} (2 VALU)
__device__ __forceinline__ f32x2 bf2pair(uint32_t w) {
  f32x2 r;
  r.x = __uint_as_float(w << 16);
  r.y = __uint_as_float(w & 0xFFFF0000u);
  return r;
}

// W1 [256][128] fp32 -> bf16 "fragment-sequential" image (64KB) in ws.
// Chunk index = (kk*8 + f)*64 + lane, lane = (g<<4)|c. Chunk holds the 8
// B-frag elements j: W1[k = kk*32 + g*8 + j][n = f*16 + c].  (R7-verified)
__global__ void k_cvt_w1(const float* __restrict__ W1, unsigned short* __restrict__ w1s) {
  int tid = blockIdx.x * blockDim.x + threadIdx.x;   // 0..4095
  int lane = tid & 63;
  int kkf  = tid >> 6;        // kk*8 + f
  int kk = kkf >> 3, f = kkf & 7;
  int c = lane & 15, g = lane >> 4;
  int n = f * 16 + c;
  u16x8 o;
#pragma unroll
  for (int j = 0; j < 8; ++j)
    o[j] = f2bf(W1[(kk * 32 + g * 8 + j) * H2 + n]);
  ((u16x8*)w1s)[tid] = o;
}

// Permuted W2 (f32): stored position s = c*8+f  <->  logical n = f*16+c.
__global__ void k_cvt_w2p(const float* __restrict__ W2, float* __restrict__ w2p) {
  int s = threadIdx.x;   // 0..127
  w2p[s] = W2[(s & 7) * 16 + (s >> 3)];
}

// ---------------- node precompute: u = x@W1a + b1, v = x@W1b (bf16, permuted cols) ----
__global__ __launch_bounds__(256, 4)
void k_uv(const float* __restrict__ x,
          const unsigned short* __restrict__ w1ws,
          const float* __restrict__ b1,
          unsigned short* __restrict__ u,
          unsigned short* __restrict__ v,
          int nNodes)
{
  __shared__ alignas(16) unsigned short w1t[H2 * 256];   // 64KB fragment image
  const int t0 = threadIdx.x, lane = t0 & 63, wid = t0 >> 6;
  const int c = lane & 15, g = lane >> 4;

#pragma unroll
  for (int i = 0; i < 16; ++i) {
    int idx = i * 256 + t0;
    ((u16x8*)w1t)[idx] = ((const u16x8*)w1ws)[idx];
  }

  const int nb = blockIdx.x * 128 + wid * 32;
  s16x8 af[4][2];
#pragma unroll
  for (int m = 0; m < 2; ++m) {
    int node = nb + m * 16 + c;
    node = node < nNodes ? node : nNodes - 1;
    const float* xp = x + (size_t)node * D_FEAT;
#pragma unroll
    for (int kk = 0; kk < 4; ++kk) {
      const f32x4* q = (const f32x4*)(xp + kk * 32 + g * 8);
      f32x4 a = q[0], b = q[1];
      s16x8 vv;
      vv[0] = (short)f2bf(a[0]); vv[1] = (short)f2bf(a[1]);
      vv[2] = (short)f2bf(a[2]); vv[3] = (short)f2bf(a[3]);
      vv[4] = (short)f2bf(b[0]); vv[5] = (short)f2bf(b[1]);
      vv[6] = (short)f2bf(b[2]); vv[7] = (short)f2bf(b[3]);
      af[kk][m] = vv;
    }
  }
  float b1v[8];
#pragma unroll
  for (int f = 0; f < 8; ++f) b1v[f] = b1[f * 16 + c];

  __syncthreads();
  const unsigned short* bbase = w1t + (unsigned)lane * 8;   // lane*16B

  f32x4 acc[2][8];

  // ---- u pass: acc init = b1, K chunks 0..3 ----
#pragma unroll
  for (int m = 0; m < 2; ++m)
#pragma unroll
    for (int f = 0; f < 8; ++f) {
      f32x4 z = {b1v[f], b1v[f], b1v[f], b1v[f]};
      acc[m][f] = z;
    }
#pragma unroll
  for (int kk = 0; kk < 4; ++kk)
#pragma unroll
    for (int f = 0; f < 8; ++f) {
      s16x8 bfrag = *(const s16x8*)(bbase + (kk * 8 + f) * 512);
#pragma unroll
      for (int m = 0; m < 2; ++m)
        acc[m][f] = __builtin_amdgcn_mfma_f32_16x16x32_bf16(af[kk][m], bfrag, acc[m][f], 0, 0, 0);
    }
#pragma unroll
  for (int m = 0; m < 2; ++m)
#pragma unroll
    for (int r = 0; r < 4; ++r) {
      int node = nb + m * 16 + g * 4 + r;
      if (node < nNodes) {
        u16x8 o;
#pragma unroll
        for (int f = 0; f < 8; ++f) o[f] = f2bf(acc[m][f][r]);
        *(u16x8*)(u + (size_t)node * H2 + c * 8) = o;
      }
    }

  // ---- v pass: acc init = 0, K chunks 4..7 ----
#pragma unroll
  for (int m = 0; m < 2; ++m)
#pragma unroll
    for (int f = 0; f < 8; ++f) {
      f32x4 z = {0.f, 0.f, 0.f, 0.f};
      acc[m][f] = z;
    }
#pragma unroll
  for (int kk = 0; kk < 4; ++kk)
#pragma unroll
    for (int f = 0; f < 8; ++f) {
      s16x8 bfrag = *(const s16x8*)(bbase + ((kk + 4) * 8 + f) * 512);
#pragma unroll
      for (int m = 0; m < 2; ++m)
        acc[m][f] = __builtin_amdgcn_mfma_f32_16x16x32_bf16(af[kk][m], bfrag, acc[m][f], 0, 0, 0);
    }
#pragma unroll
  for (int m = 0; m < 2; ++m)
#pragma unroll
    for (int r = 0; r < 4; ++r) {
      int node = nb + m * 16 + g * 4 + r;
      if (node < nNodes) {
        u16x8 o;
#pragma unroll
        for (int f = 0; f < 8; ++f) o[f] = f2bf(acc[m][f][r]);
        *(u16x8*)(v + (size_t)node * H2 + c * 8) = o;
      }
    }
}

// ---------------- edge stage v3: row-coalesced gathers + packed-f32 VALU ----------------
// Wave = 8 edges: lane = eo*16 + p. 16 lanes x 16B = one full 256B u/v row per
// load instruction (2x128B line requests). Math uses v_pk_{add,max,fma}_f32:
// per 2 elements = 4 extract + 3 packed ops (was 10 scalar ops).
__global__ __launch_bounds__(256, 8)
void k_edge(const unsigned short* __restrict__ u,
            const unsigned short* __restrict__ v,
            const int* __restrict__ eli,
            const float* __restrict__ w2p,
            const float* __restrict__ b2,
            float* __restrict__ out, int E, int nNodes)
{
  const int t0 = threadIdx.x, lane = t0 & 63, wid = t0 >> 6;
  const int p  = lane & 15;       // 16B chunk within row
  const int eo = lane >> 4;       // edge within 4-group
  const int ewave = blockIdx.x * 32 + wid * 8;

  // lane's 4 W2 coefficient pairs in stored order (32B, L1-resident)
  const f32x2* w2q = (const f32x2*)(w2p + p * 8);
  const f32x2 wp0 = w2q[0], wp1 = w2q[1], wp2 = w2q[2], wp3 = w2q[3];
  const float b2s = b2[0];

  u16x8 uu[2], vv[2];
  int eidx[2];
#pragma unroll
  for (int m = 0; m < 2; ++m) {
    int e = ewave + m * 4 + eo;
    eidx[m] = e;
    int ec = e < E ? e : E - 1;
    int nr = eli[ec], nc = eli[E + ec];
    nr = nr < 0 ? 0 : (nr >= nNodes ? nNodes - 1 : nr);
    nc = nc < 0 ? 0 : (nc >= nNodes ? nNodes - 1 : nc);
    uu[m] = *(const u16x8*)(u + (size_t)nr * H2 + p * 8);
    vv[m] = *(const u16x8*)(v + (size_t)nc * H2 + p * 8);
  }

#pragma unroll
  for (int m = 0; m < 2; ++m) {
    u32x4 uw = __builtin_bit_cast(u32x4, uu[m]);
    u32x4 vw = __builtin_bit_cast(u32x4, vv[m]);
    f32x2 acc2 = {0.f, 0.f};
    const f32x2 z2 = {0.f, 0.f};
    const f32x2 wp[4] = {wp0, wp1, wp2, wp3};
#pragma unroll
    for (int t = 0; t < 4; ++t) {
      f32x2 s2 = bf2pair(uw[t]) + bf2pair(vw[t]);       // v_pk_add_f32
      f32x2 h2 = __builtin_elementwise_max(s2, z2);     // v_pk_max_f32
      acc2 = __builtin_elementwise_fma(h2, wp[t], acc2);// v_pk_fma_f32
    }
    float s = acc2.x + acc2.y;
    // reduce over the 16 p-lanes of this edge
    s += __shfl_xor(s, 1, 64);
    s += __shfl_xor(s, 2, 64);
    s += __shfl_xor(s, 4, 64);
    s += __shfl_xor(s, 8, 64);
    if (p == 0 && eidx[m] < E) out[eidx[m]] = s + b2s;
  }
}

// ---------------- fallback (ws too small): R7 monolithic, fp32 paths ----------------
__global__ __launch_bounds__(512, 4)
void k_fallback(const float* __restrict__ xf,
                const int* __restrict__ eli,
                const float* __restrict__ W1,
                const float* __restrict__ b1,
                const float* __restrict__ W2,
                const float* __restrict__ b2,
                float* __restrict__ out, int E, int nNodes)
{
  __shared__ alignas(16) unsigned short w1t[H2 * 256];
  const int t0 = threadIdx.x, lane = t0 & 63, wid = t0 >> 6;
  const int c = lane & 15, g = lane >> 4;

#pragma unroll
  for (int i = 0; i < 8; ++i) {
    int chunk = i * 512 + t0;
    int cl = chunk & 63, kkf = chunk >> 6;
    int kk = kkf >> 3, f = kkf & 7;
    int cc = cl & 15, gg = cl >> 4;
    int n = f * 16 + cc;
    u16x8 o;
#pragma unroll
    for (int j = 0; j < 8; ++j)
      o[j] = f2bf(W1[(kk * 32 + gg * 8 + j) * H2 + n]);
    ((u16x8*)w1t)[chunk] = o;
  }

  const int gbase = blockIdx.x * 256 + wid * 32;
  unsigned ro[2], co[2];
#pragma unroll
  for (int m = 0; m < 2; ++m) {
    int e = gbase + m * 16 + c;
    e = e < E ? e : E - 1;
    int nr = eli[e], nc = eli[E + e];
    nr = nr < 0 ? 0 : (nr >= nNodes ? nNodes - 1 : nr);
    nc = nc < 0 ? 0 : (nc >= nNodes ? nNodes - 1 : nc);
    ro[m] = (unsigned)nr * D_FEAT + g * 8;
    co[m] = (unsigned)nc * D_FEAT + g * 8;
  }
  __syncthreads();

  auto loadA = [&](int kk, s16x8* dst) {
#pragma unroll
    for (int m = 0; m < 2; ++m) {
      unsigned off = (kk < 4 ? ro[m] : co[m]) + (unsigned)((kk & 3) * 32);
      const f32x4* q = (const f32x4*)(xf + off);
      f32x4 a = q[0], b = q[1];
      s16x8 vv2;
      vv2[0] = (short)f2bf(a[0]); vv2[1] = (short)f2bf(a[1]);
      vv2[2] = (short)f2bf(a[2]); vv2[3] = (short)f2bf(a[3]);
      vv2[4] = (short)f2bf(b[0]); vv2[5] = (short)f2bf(b[1]);
      vv2[6] = (short)f2bf(b[2]); vv2[7] = (short)f2bf(b[3]);
      dst[m] = vv2;
    }
  };

  f32x4 acc[2][8];
#pragma unroll
  for (int m = 0; m < 2; ++m)
#pragma unroll
    for (int f = 0; f < 8; ++f) {
      f32x4 z = {0.f, 0.f, 0.f, 0.f};
      acc[m][f] = z;
    }
  s16x8 abuf[2][2];
  loadA(0, abuf[0]);
  loadA(1, abuf[1]);
  const unsigned short* bbase = w1t + (unsigned)lane * 8;
#pragma unroll
  for (int kk = 0; kk < 8; ++kk) {
#pragma unroll
    for (int f = 0; f < 8; ++f) {
      s16x8 bfrag = *(const s16x8*)(bbase + (kk * 8 + f) * 512);
#pragma unroll
      for (int m = 0; m < 2; ++m)
        acc[m][f] = __builtin_amdgcn_mfma_f32_16x16x32_bf16(abuf[kk & 1][m], bfrag, acc[m][f], 0, 0, 0);
    }
    if (kk < 6) loadA(kk + 2, abuf[kk & 1]);
  }
  float b1v[8], w2v[8];
#pragma unroll
  for (int f = 0; f < 8; ++f) { b1v[f] = b1[f * 16 + c]; w2v[f] = W2[f * 16 + c]; }
  const float b2s = b2[0];
#pragma unroll
  for (int m = 0; m < 2; ++m) {
    float sr[4];
#pragma unroll
    for (int r = 0; r < 4; ++r) {
      float s = 0.f;
#pragma unroll
      for (int f = 0; f < 8; ++f) {
        float h = acc[m][f][r] + b1v[f];
        h = h > 0.f ? h : 0.f;
        s += h * w2v[f];
      }
#pragma unroll
      for (int msk = 1; msk < 16; msk <<= 1) s += __shfl_xor(s, msk, 64);
      sr[r] = s;
    }
    int ebase2 = gbase + m * 16 + g * 4;
    if (c == 0 && ebase2 < E) {
      f32x4 o = {sr[0] + b2s, sr[1] + b2s, sr[2] + b2s, sr[3] + b2s};
      *(f32x4*)(out + ebase2) = o;
    }
  }
}

extern "C" void kernel_launch(void* const* d_in, const int* in_sizes, int n_in,
                              void* d_out, int out_size, void* d_ws, size_t ws_size,
                              hipStream_t stream) {
  const float* x   = (const float*)d_in[0];
  const int*   eli = (const int*)d_in[1];     // int32 per harness contract
  const float* W1  = (const float*)d_in[2];
  const float* b1  = (const float*)d_in[3];
  const float* W2  = (const float*)d_in[4];
  const float* b2  = (const float*)d_in[5];
  float* out = (float*)d_out;

  const int E      = in_sizes[1] / 2;
  const int nNodes = in_sizes[0] / D_FEAT;

  const size_t ubytes = (size_t)nNodes * H2 * 2;      // 25.6MB each
  const size_t need   = 2 * ubytes + 65536 + 512;

  if (ws_size >= need) {
    unsigned short* us  = (unsigned short*)d_ws;
    unsigned short* vs  = (unsigned short*)((char*)d_ws + ubytes);
    unsigned short* w1f = (unsigned short*)((char*)d_ws + 2 * ubytes);
    float*          w2p = (float*)((char*)d_ws + 2 * ubytes + 65536);

    k_cvt_w1<<<16, 256, 0, stream>>>(W1, w1f);
    k_cvt_w2p<<<1, 128, 0, stream>>>(W2, w2p);
    k_uv<<<(nNodes + 127) / 128, 256, 0, stream>>>(x, w1f, b1, us, vs, nNodes);
    k_edge<<<(E + 31) / 32, 256, 0, stream>>>(us, vs, eli, w2p, b2, out, E, nNodes);
  } else {
    k_fallback<<<(E + 255) / 256, 512, 0, stream>>>(x, eli, W1, b1, W2, b2, out, E, nNodes);
  }
}

// Round 13
// 129.516 us; speedup vs baseline: 1.0095x; 1.0095x over previous
//
#include <hip/hip_runtime.h>
#include <hip/hip_bf16.h>
#include <stdint.h>

typedef __attribute__((ext_vector_type(8))) short s16x8;          // 8 bf16 (4 VGPRs)
typedef __attribute__((ext_vector_type(8))) unsigned short u16x8;
typedef __attribute__((ext_vector_type(4))) float f32x4;
typedef __attribute__((ext_vector_type(8))) _Float16 h16x8;       // 8 fp16 (16B)
typedef __attribute__((ext_vector_type(2))) _Float16 h16x2;

#define D_FEAT 128
#define H2 128

__device__ __forceinline__ unsigned short f2bf(float f) {
  uint32_t u = __float_as_uint(f);
  return (unsigned short)((u + 0x7fffu + ((u >> 16) & 1u)) >> 16);  // RNE
}

__device__ __forceinline__ float dot2acc(h16x2 a, h16x2 b, float c) {
#if __has_builtin(__builtin_amdgcn_fdot2)
  return __builtin_amdgcn_fdot2(a, b, c, false);     // v_dot2_f32_f16
#else
  return c + (float)a.x * (float)b.x + (float)a.y * (float)b.y;
#endif
}

// DPP add over the shuffled value; all our waves are fully active.
#define DPP_ADD(s, ctrl) \
  ((s) + __int_as_float(__builtin_amdgcn_update_dpp(0, __float_as_int(s), (ctrl), 0xF, 0xF, true)))

// ---- merged weight prep: bf16 W1 fragment image (R7 layout) + permuted packed fp16 W2 ----
// W1 image chunk = (kk*8+f)*64 + lane holds W1[k=kk*32+g*8+j][n=f*16+c], lane=(g<<4)|c.
// W2 permuted: stored s = c*8+f <-> logical n = f*16+c (matches u/v column storage).
__global__ void k_cvt(const float* __restrict__ W1, const float* __restrict__ W2,
                      unsigned short* __restrict__ w1s, _Float16* __restrict__ w2h) {
  if (blockIdx.x < 16) {
    int tid = blockIdx.x * 256 + threadIdx.x;   // 0..4095
    int lane = tid & 63;
    int kkf  = tid >> 6;
    int kk = kkf >> 3, f = kkf & 7;
    int c = lane & 15, g = lane >> 4;
    int n = f * 16 + c;
    u16x8 o;
#pragma unroll
    for (int j = 0; j < 8; ++j)
      o[j] = f2bf(W1[(kk * 32 + g * 8 + j) * H2 + n]);
    ((u16x8*)w1s)[tid] = o;
  } else {
    int s = threadIdx.x;   // 0..255, use 0..127
    if (s < 128) w2h[s] = (_Float16)W2[(s & 7) * 16 + (s >> 3)];
  }
}

// ---------------- node precompute: u = x@W1a + b1, v = x@W1b (fp16, permuted cols) ----
__global__ __launch_bounds__(256, 4)
void k_uv(const float* __restrict__ x,
          const unsigned short* __restrict__ w1ws,
          const float* __restrict__ b1,
          _Float16* __restrict__ u,
          _Float16* __restrict__ v,
          int nNodes)
{
  __shared__ alignas(16) unsigned short w1t[H2 * 256];   // 64KB fragment image
  const int t0 = threadIdx.x, lane = t0 & 63, wid = t0 >> 6;
  const int c = lane & 15, g = lane >> 4;

#pragma unroll
  for (int i = 0; i < 16; ++i) {
    int idx = i * 256 + t0;
    ((u16x8*)w1t)[idx] = ((const u16x8*)w1ws)[idx];
  }

  const int nb = blockIdx.x * 128 + wid * 32;
  s16x8 af[4][2];
#pragma unroll
  for (int m = 0; m < 2; ++m) {
    int node = nb + m * 16 + c;
    node = node < nNodes ? node : nNodes - 1;
    const float* xp = x + (size_t)node * D_FEAT;
#pragma unroll
    for (int kk = 0; kk < 4; ++kk) {
      const f32x4* q = (const f32x4*)(xp + kk * 32 + g * 8);
      f32x4 a = q[0], b = q[1];
      s16x8 vv;
      vv[0] = (short)f2bf(a[0]); vv[1] = (short)f2bf(a[1]);
      vv[2] = (short)f2bf(a[2]); vv[3] = (short)f2bf(a[3]);
      vv[4] = (short)f2bf(b[0]); vv[5] = (short)f2bf(b[1]);
      vv[6] = (short)f2bf(b[2]); vv[7] = (short)f2bf(b[3]);
      af[kk][m] = vv;
    }
  }
  float b1v[8];
#pragma unroll
  for (int f = 0; f < 8; ++f) b1v[f] = b1[f * 16 + c];

  __syncthreads();
  const unsigned short* bbase = w1t + (unsigned)lane * 8;   // lane*16B

  f32x4 acc[2][8];

  // ---- u pass: acc init = b1, K chunks 0..3 ----
#pragma unroll
  for (int m = 0; m < 2; ++m)
#pragma unroll
    for (int f = 0; f < 8; ++f) {
      f32x4 z = {b1v[f], b1v[f], b1v[f], b1v[f]};
      acc[m][f] = z;
    }
#pragma unroll
  for (int kk = 0; kk < 4; ++kk)
#pragma unroll
    for (int f = 0; f < 8; ++f) {
      s16x8 bfrag = *(const s16x8*)(bbase + (kk * 8 + f) * 512);
#pragma unroll
      for (int m = 0; m < 2; ++m)
        acc[m][f] = __builtin_amdgcn_mfma_f32_16x16x32_bf16(af[kk][m], bfrag, acc[m][f], 0, 0, 0);
    }
#pragma unroll
  for (int m = 0; m < 2; ++m)
#pragma unroll
    for (int r = 0; r < 4; ++r) {
      int node = nb + m * 16 + g * 4 + r;
      if (node < nNodes) {
        h16x8 o;
#pragma unroll
        for (int f = 0; f < 8; ++f) o[f] = (_Float16)acc[m][f][r];
        *(h16x8*)(u + (size_t)node * H2 + c * 8) = o;
      }
    }

  // ---- v pass: acc init = 0, K chunks 4..7 ----
#pragma unroll
  for (int m = 0; m < 2; ++m)
#pragma unroll
    for (int f = 0; f < 8; ++f) {
      f32x4 z = {0.f, 0.f, 0.f, 0.f};
      acc[m][f] = z;
    }
#pragma unroll
  for (int kk = 0; kk < 4; ++kk)
#pragma unroll
    for (int f = 0; f < 8; ++f) {
      s16x8 bfrag = *(const s16x8*)(bbase + ((kk + 4) * 8 + f) * 512);
#pragma unroll
      for (int m = 0; m < 2; ++m)
        acc[m][f] = __builtin_amdgcn_mfma_f32_16x16x32_bf16(af[kk][m], bfrag, acc[m][f], 0, 0, 0);
    }
#pragma unroll
  for (int m = 0; m < 2; ++m)
#pragma unroll
    for (int r = 0; r < 4; ++r) {
      int node = nb + m * 16 + g * 4 + r;
      if (node < nNodes) {
        h16x8 o;
#pragma unroll
        for (int f = 0; f < 8; ++f) o[f] = (_Float16)acc[m][f][r];
        *(h16x8*)(v + (size_t)node * H2 + c * 8) = o;
      }
    }
}

// ---------------- edge stage v4: fp16 packed math + DPP reduce ----------------
// Wave = 16 edges: lane = eo*16 + p. 16 lanes x 16B = one full 256B u/v row per
// load instruction. Math: v_pk_add_f16 + v_pk_max_f16 + v_dot2_f32_f16
// (3 VALU / 2 elements). Reduce: 4 DPP adds (VALU-only, no DS pipe).
__global__ __launch_bounds__(256, 8)
void k_edge(const _Float16* __restrict__ u,
            const _Float16* __restrict__ v,
            const int* __restrict__ eli,
            const _Float16* __restrict__ w2h,
            const float* __restrict__ b2,
            float* __restrict__ out, int E, int nNodes)
{
  const int t0 = threadIdx.x, lane = t0 & 63, wid = t0 >> 6;
  const int p  = lane & 15;       // 16B chunk within row
  const int eo = lane >> 4;       // edge within 4-group
  const int ewave = blockIdx.x * 64 + wid * 16;

  const h16x8 wv = *(const h16x8*)(w2h + p * 8);   // lane's 8 W2 coeffs (fp16)
  const float b2s = b2[0];

  h16x8 uu[4], vv[4];
  int eidx[4];
#pragma unroll
  for (int m = 0; m < 4; ++m) {
    int e = ewave + m * 4 + eo;
    eidx[m] = e;
    int ec = e < E ? e : E - 1;
    int nr = eli[ec], nc = eli[E + ec];
    nr = nr < 0 ? 0 : (nr >= nNodes ? nNodes - 1 : nr);
    nc = nc < 0 ? 0 : (nc >= nNodes ? nNodes - 1 : nc);
    uu[m] = *(const h16x8*)(u + (size_t)nr * H2 + p * 8);
    vv[m] = *(const h16x8*)(v + (size_t)nc * H2 + p * 8);
  }

  const h16x8 z8 = {};
#pragma unroll
  for (int m = 0; m < 4; ++m) {
    h16x8 h8 = __builtin_elementwise_max(uu[m] + vv[m], z8);  // pk_add + pk_max
    float s = 0.f;
#pragma unroll
    for (int t = 0; t < 4; ++t) {
      h16x2 hp = {h8[2 * t], h8[2 * t + 1]};
      h16x2 wp = {wv[2 * t], wv[2 * t + 1]};
      s = dot2acc(hp, wp, s);                                  // v_dot2_f32_f16
    }
    // reduce over the 16 p-lanes: quad xor1, xor2, half-mirror, mirror
    s = DPP_ADD(s, 0xB1);
    s = DPP_ADD(s, 0x4E);
    s = DPP_ADD(s, 0x141);
    s = DPP_ADD(s, 0x140);
    if (p == 0 && eidx[m] < E) out[eidx[m]] = s + b2s;
  }
}

// ---------------- fallback (ws too small): R7 monolithic, fp32 paths ----------------
__global__ __launch_bounds__(512, 4)
void k_fallback(const float* __restrict__ xf,
                const int* __restrict__ eli,
                const float* __restrict__ W1,
                const float* __restrict__ b1,
                const float* __restrict__ W2,
                const float* __restrict__ b2,
                float* __restrict__ out, int E, int nNodes)
{
  __shared__ alignas(16) unsigned short w1t[H2 * 256];
  const int t0 = threadIdx.x, lane = t0 & 63, wid = t0 >> 6;
  const int c = lane & 15, g = lane >> 4;

#pragma unroll
  for (int i = 0; i < 8; ++i) {
    int chunk = i * 512 + t0;
    int cl = chunk & 63, kkf = chunk >> 6;
    int kk = kkf >> 3, f = kkf & 7;
    int cc = cl & 15, gg = cl >> 4;
    int n = f * 16 + cc;
    u16x8 o;
#pragma unroll
    for (int j = 0; j < 8; ++j)
      o[j] = f2bf(W1[(kk * 32 + gg * 8 + j) * H2 + n]);
    ((u16x8*)w1t)[chunk] = o;
  }

  const int gbase = blockIdx.x * 256 + wid * 32;
  unsigned ro[2], co[2];
#pragma unroll
  for (int m = 0; m < 2; ++m) {
    int e = gbase + m * 16 + c;
    e = e < E ? e : E - 1;
    int nr = eli[e], nc = eli[E + e];
    nr = nr < 0 ? 0 : (nr >= nNodes ? nNodes - 1 : nr);
    nc = nc < 0 ? 0 : (nc >= nNodes ? nNodes - 1 : nc);
    ro[m] = (unsigned)nr * D_FEAT + g * 8;
    co[m] = (unsigned)nc * D_FEAT + g * 8;
  }
  __syncthreads();

  auto loadA = [&](int kk, s16x8* dst) {
#pragma unroll
    for (int m = 0; m < 2; ++m) {
      unsigned off = (kk < 4 ? ro[m] : co[m]) + (unsigned)((kk & 3) * 32);
      const f32x4* q = (const f32x4*)(xf + off);
      f32x4 a = q[0], b = q[1];
      s16x8 vv2;
      vv2[0] = (short)f2bf(a[0]); vv2[1] = (short)f2bf(a[1]);
      vv2[2] = (short)f2bf(a[2]); vv2[3] = (short)f2bf(a[3]);
      vv2[4] = (short)f2bf(b[0]); vv2[5] = (short)f2bf(b[1]);
      vv2[6] = (short)f2bf(b[2]); vv2[7] = (short)f2bf(b[3]);
      dst[m] = vv2;
    }
  };

  f32x4 acc[2][8];
#pragma unroll
  for (int m = 0; m < 2; ++m)
#pragma unroll
    for (int f = 0; f < 8; ++f) {
      f32x4 z = {0.f, 0.f, 0.f, 0.f};
      acc[m][f] = z;
    }
  s16x8 abuf[2][2];
  loadA(0, abuf[0]);
  loadA(1, abuf[1]);
  const unsigned short* bbase = w1t + (unsigned)lane * 8;
#pragma unroll
  for (int kk = 0; kk < 8; ++kk) {
#pragma unroll
    for (int f = 0; f < 8; ++f) {
      s16x8 bfrag = *(const s16x8*)(bbase + (kk * 8 + f) * 512);
#pragma unroll
      for (int m = 0; m < 2; ++m)
        acc[m][f] = __builtin_amdgcn_mfma_f32_16x16x32_bf16(abuf[kk & 1][m], bfrag, acc[m][f], 0, 0, 0);
    }
    if (kk < 6) loadA(kk + 2, abuf[kk & 1]);
  }
  float b1v[8], w2v[8];
#pragma unroll
  for (int f = 0; f < 8; ++f) { b1v[f] = b1[f * 16 + c]; w2v[f] = W2[f * 16 + c]; }
  const float b2s = b2[0];
#pragma unroll
  for (int m = 0; m < 2; ++m) {
    float sr[4];
#pragma unroll
    for (int r = 0; r < 4; ++r) {
      float s = 0.f;
#pragma unroll
      for (int f = 0; f < 8; ++f) {
        float h = acc[m][f][r] + b1v[f];
        h = h > 0.f ? h : 0.f;
        s += h * w2v[f];
      }
#pragma unroll
      for (int msk = 1; msk < 16; msk <<= 1) s += __shfl_xor(s, msk, 64);
      sr[r] = s;
    }
    int ebase2 = gbase + m * 16 + g * 4;
    if (c == 0 && ebase2 < E) {
      f32x4 o = {sr[0] + b2s, sr[1] + b2s, sr[2] + b2s, sr[3] + b2s};
      *(f32x4*)(out + ebase2) = o;
    }
  }
}

extern "C" void kernel_launch(void* const* d_in, const int* in_sizes, int n_in,
                              void* d_out, int out_size, void* d_ws, size_t ws_size,
                              hipStream_t stream) {
  const float* x   = (const float*)d_in[0];
  const int*   eli = (const int*)d_in[1];     // int32 per harness contract
  const float* W1  = (const float*)d_in[2];
  const float* b1  = (const float*)d_in[3];
  const float* W2  = (const float*)d_in[4];
  const float* b2  = (const float*)d_in[5];
  float* out = (float*)d_out;

  const int E      = in_sizes[1] / 2;
  const int nNodes = in_sizes[0] / D_FEAT;

  const size_t ubytes = (size_t)nNodes * H2 * 2;      // 25.6MB each (fp16)
  const size_t need   = 2 * ubytes + 65536 + 512;

  if (ws_size >= need) {
    _Float16*       us  = (_Float16*)d_ws;
    _Float16*       vs  = (_Float16*)((char*)d_ws + ubytes);
    unsigned short* w1f = (unsigned short*)((char*)d_ws + 2 * ubytes);
    _Float16*       w2h = (_Float16*)((char*)d_ws + 2 * ubytes + 65536);

    k_cvt<<<17, 256, 0, stream>>>(W1, W2, w1f, w2h);
    k_uv<<<(nNodes + 127) / 128, 256, 0, stream>>>(x, w1f, b1, us, vs, nNodes);
    k_edge<<<(E + 63) / 64, 256, 0, stream>>>(us, vs, eli, w2h, b2, out, E, nNodes);
  } else {
    k_fallback<<<(E + 255) / 256, 512, 0, stream>>>(x, eli, W1, b1, W2, b2, out, E, nNodes);
  }
}